// Round 1
// baseline (643.164 us; speedup 1.0000x reference)
//
#include <hip/hip_runtime.h>
#include <stdint.h>

#define NEURONS 512
#define SYN     784
#define TIN     500
#define TP      522
#define TPAD    528
#define BATCH   64
#define NCOL    (BATCH*TPAD)   // 33792
#define XW2     18             // xbT words per (b,*,s): word0 guard, 1..16 data, 17 guard
#define NKK     98             // K iterations (6272 / 64)

typedef int i32x4 __attribute__((ext_vector_type(4)));

// ---------------------------------------------------------------- A pack
// One-hot int8 weights, MFMA-fragment-packed (verified R3/R4):
// uint2 slot u <-> (kk, rowblk, quad, m=l15, half): byte k = s*8+w mapping.
__global__ void k_apack(const int* __restrict__ w, uint2* __restrict__ apk) {
    int u = blockIdx.x * 256 + threadIdx.x;            // 401408 slots
    int half = u & 1, m = (u >> 1) & 15, quad = (u >> 5) & 3;
    int rowblk = (u >> 7) & 31, kk = u >> 12;
    int n = rowblk * 16 + m;
    int s = kk * 8 + quad * 2 + half;
    int wv = w[n * SYN + s];
    uint2 v;
    v.x = (wv < 4)  ? (1u << (8 * wv))       : 0u;
    v.y = (wv >= 4) ? (1u << (8 * (wv - 4))) : 0u;
    apk[u] = v;
}

// ---------------------------------------------------------------- spike bits, transposed
// xbT[(b*18 + word)*784 + s]; word 0,17 guards; word w in 1..16: bit j = spike at
// tau=(w-1)*32+j. Coalesced: LDS nibble transpose, 16 rows per 256-thr block.
__global__ void k_xbitsT(const float* __restrict__ x, uint32_t* __restrict__ xbT) {
    __shared__ unsigned char nib[16][128];
    int tid = threadIdx.x;
    int r0  = blockIdx.x * 16;                         // 3136 blocks, 784%16==0 -> b uniform
    for (int e = tid; e < 2048; e += 256) {
        int row = e >> 7, q4 = e & 127;
        unsigned char v = 0;
        if (q4 < 125) {
            float4 f = *(const float4*)(x + (size_t)(r0 + row) * TIN + q4 * 4);
            v = (unsigned char)((f.x != 0.f) | ((f.y != 0.f) << 1) |
                                ((f.z != 0.f) << 2) | ((f.w != 0.f) << 3));
        }
        nib[row][q4] = v;
    }
    __syncthreads();
    int row = tid >> 4, d = tid & 15;
    uint64_t u = *(const uint64_t*)&nib[row][d * 8];
    uint32_t wd = 0;
#pragma unroll
    for (int q = 0; q < 8; ++q)
        wd |= ((uint32_t)((u >> (8 * q)) & 0xFull)) << (4 * q);
    if (d == 15) wd &= 0xFFFFFu;                       // taus 480..499 only
    int grow = r0 + row;
    int b = grow / SYN, s = grow - b * SYN;
    xbT[(size_t)(b * XW2 + 1 + d) * SYN + s] = wd;
    if (d == 0) {
        xbT[(size_t)(b * XW2) * SYN + s] = 0u;         // guard word 0
        xbT[(size_t)(b * XW2 + 17) * SYN + s] = 0u;    // guard word 17
    }
}

// ---------------------------------------------------------------- fused GEMM + argmax
// Row-complete blocks: 512 rows x 64 cols, 4 waves (each 128 rows x 64 cols).
// B windows built ONCE per block per K-step (256 thr x 1 staging write) into
// double-buffered LDS (80B col stride, bank-balanced), shared by all waves.
// One barrier per K-step; build(kk+1) overlaps MFMA(kk).
__global__ __launch_bounds__(256, 2) void k_gemm(
    const i32x4*    __restrict__ Apk4,
    const uint32_t* __restrict__ xbT,
    const int*      __restrict__ wk,
    unsigned long long* __restrict__ partial)
{
    __shared__ uint2 T0[2048];           // taps 0..10 sums, packed u8 x8
    __shared__ uint2 T1[1024];           // taps 11..20
    __shared__ uint2 tapv[21];
    __shared__ i32x4 Bst[2][64 * 5];     // B staging: col stride 5 x i32x4 = 80B
    __shared__ unsigned long long red[64 * 17];

    const int tid  = threadIdx.x;
    const int lane = tid & 63;
    const int wn   = tid >> 6;           // wave id -> row group (rb0)
    const int quad = lane >> 4, l15 = lane & 15;
    const int col0 = blockIdx.x * 64;
    const int rb0  = wn * 8;

    if (tid < 21) {
        uint32_t lo = 0, hi = 0;
        for (int q = 0; q < 4; ++q) {
            lo |= ((uint32_t)wk[q * 21 + tid]) << (8 * q);
            hi |= ((uint32_t)wk[(q + 4) * 21 + tid]) << (8 * q);
        }
        tapv[tid] = make_uint2(lo, hi);
    }
    __syncthreads();
    for (int e = tid; e < 3072; e += 256) {
        int base_t = (e < 2048) ? 0 : 11;
        uint32_t mm = (e < 2048) ? e : (e - 2048);
        uint2 a = make_uint2(0u, 0u);
        while (mm) {
            int p = __builtin_ctz(mm);
            uint2 tv = tapv[base_t + p];
            a.x += tv.x; a.y += tv.y;
            mm &= mm - 1;
        }
        if (e < 2048) T0[e] = a; else T1[e - 2048] = a;
    }

    // build-thread setup: one (column, synapse-pair) per thread
    const int bc = tid & 63;             // column in block
    const int sp = tid >> 6;             // synapse pair 0..3 (== MFMA quad on read side)
    uint32_t xbase, xsh;
    {
        int c  = col0 + bc;
        int b  = c / TPAD, t = c - b * TPAD;
        int bp = t + 11;                 // window covers flat bits bp..bp+20
        xbase = (uint32_t)((b * XW2 + (bp >> 5)) * SYN + sp * 2);
        xsh   = (uint32_t)(bp & 31);
    }
    __syncthreads();                     // T0/T1 ready

    i32x4 acc[8][4];
#pragma unroll
    for (int i = 0; i < 8; ++i)
#pragma unroll
        for (int j = 0; j < 4; ++j) { i32x4 z = {0, 0, 0, 0}; acc[i][j] = z; }

    // prologue: stage B(0) into Bst[0]
    {
        const uint2* px = (const uint2*)(xbT + xbase);
        uint2 lo = px[0], hi = px[SYN / 2];
        uint32_t w0 = __builtin_amdgcn_alignbit(hi.x, lo.x, xsh) & 0x1FFFFFu;
        uint32_t w1 = __builtin_amdgcn_alignbit(hi.y, lo.y, xsh) & 0x1FFFFFu;
        uint2 u0 = T0[w0 & 2047], v0 = T1[w0 >> 11];
        uint2 u1 = T0[w1 & 2047], v1 = T1[w1 >> 11];
        i32x4 bb;
        bb[0] = (int)(u0.x + v0.x); bb[1] = (int)(u0.y + v0.y);
        bb[2] = (int)(u1.x + v1.x); bb[3] = (int)(u1.y + v1.y);
        Bst[0][bc * 5 + sp] = bb;
    }
    __syncthreads();

    for (int kk = 0; kk < NKK; ++kk) {
        const int p = kk & 1;
        // A fragments for this K-step (global, L1/L2-hit)
        i32x4 af[8];
#pragma unroll
        for (int i = 0; i < 8; ++i)
            af[i] = Apk4[(size_t)(kk * 32 + rb0 + i) * 64 + lane];
        // B fragments from staging (issued before build so MFMA's lgkmcnt
        // wait doesn't chain on the kk+1 lookup latency)
        i32x4 bf[4];
#pragma unroll
        for (int j = 0; j < 4; ++j)
            bf[j] = Bst[p][(j * 16 + l15) * 5 + quad];
        // stage B(kk+1) into the other buffer (overlaps MFMAs below)
        if (kk + 1 < NKK) {
            const uint2* px = (const uint2*)(xbT + xbase + (kk + 1) * 8);
            uint2 lo = px[0], hi = px[SYN / 2];
            uint32_t w0 = __builtin_amdgcn_alignbit(hi.x, lo.x, xsh) & 0x1FFFFFu;
            uint32_t w1 = __builtin_amdgcn_alignbit(hi.y, lo.y, xsh) & 0x1FFFFFu;
            uint2 u0 = T0[w0 & 2047], v0 = T1[w0 >> 11];
            uint2 u1 = T0[w1 & 2047], v1 = T1[w1 >> 11];
            i32x4 bb;
            bb[0] = (int)(u0.x + v0.x); bb[1] = (int)(u0.y + v0.y);
            bb[2] = (int)(u1.x + v1.x); bb[3] = (int)(u1.y + v1.y);
            Bst[p ^ 1][bc * 5 + sp] = bb;
        }
#pragma unroll
        for (int i = 0; i < 8; ++i)
#pragma unroll
            for (int j = 0; j < 4; ++j)
                acc[i][j] = __builtin_amdgcn_mfma_i32_16x16x64_i8(af[i], bf[j], acc[i][j], 0, 0, 0);
        __syncthreads();                 // B(kk+1) complete; bf(kk) reads drained
    }

    // epilogue: per-lane best over its 32 rows per column, cross-wave via LDS
#pragma unroll
    for (int j = 0; j < 4; ++j) {
        unsigned long long bp = 0ull;
#pragma unroll
        for (int i = 0; i < 8; ++i)
#pragma unroll
            for (int r = 0; r < 4; ++r) {
                int grow = wn * 128 + i * 16 + quad * 4 + r;
                unsigned long long pk =
                    (((unsigned long long)(uint32_t)acc[i][j][r]) << 32) |
                    (unsigned long long)(uint32_t)(511 - grow);
                bp = pk > bp ? pk : bp;
            }
        red[(j * 16 + l15) * 17 + wn * 4 + quad] = bp;
    }
    __syncthreads();
    if (tid < 64) {
        unsigned long long b = red[tid * 17];
#pragma unroll
        for (int u = 1; u < 16; ++u) {
            unsigned long long v = red[tid * 17 + u];
            b = v > b ? v : b;
        }
        atomicMax(&partial[col0 + tid], b);
    }
}

// ---------------------------------------------------------------- fire ballot
__global__ void k_fire(const unsigned long long* __restrict__ partial,
                       int* __restrict__ argT, unsigned long long* __restrict__ fireM) {
    int id   = blockIdx.x * 4 + (threadIdx.x >> 6);   // 576 = 64 b x 9 chunks
    int lane = threadIdx.x & 63;
    int b    = id / 9, ch = id - b * 9;
    int t    = ch * 64 + lane;
    int col  = b * TPAD + (t < TPAD ? t : TPAD - 1);
    unsigned long long pv = partial[col];
    int best = (int)(pv >> 32);
    int arg  = 511 - (int)(pv & 0xFFFFFFFFull);
    argT[id * 64 + lane] = arg;
    unsigned long long f = __ballot((t < TP) && (best > 40));
    if (lane == 0) fireM[id] = f;
}

// ---------------------------------------------------------------- depression walk
__global__ void k_scan(const unsigned long long* __restrict__ fireM,
                       const int* __restrict__ argT, float* __restrict__ out) {
    int b = threadIdx.x;  // 64 lanes = 64 batches
    unsigned long long fm[9];
#pragma unroll
    for (int c = 0; c < 9; ++c) fm[c] = fireM[b * 9 + c];
    unsigned short ts[26];
    int nf = 0, dep = 0;
    for (int c = 0; c < 9; ++c) {
        unsigned long long mm = fm[c];
        int pos = 0;
        while (pos < 64) {
            if (dep > 0) {
                int adv = dep < (64 - pos) ? dep : (64 - pos);
                dep -= adv; pos += adv; mm >>= adv;    // adv <= 21 < 64
                continue;
            }
            if (mm == 0) break;
            int z = __builtin_ctzll(mm);
            pos += z; mm >>= z;
            ts[nf++] = (unsigned short)(c * 64 + pos);
            dep = 21; ++pos; mm >>= 1;
        }
    }
    for (int i = 0; i < nf; ++i) {
        int t = ts[i];
        int a = argT[(b * 9 + (t >> 6)) * 64 + (t & 63)];
        out[(size_t)b * (NEURONS * TP) + (size_t)a * TP + t] = 1.0f;
    }
}

extern "C" void kernel_launch(void* const* d_in, const int* in_sizes, int n_in,
                              void* d_out, int out_size, void* d_ws, size_t ws_size,
                              hipStream_t stream) {
    const float* x      = (const float*)d_in[0];
    const int*   weight = (const int*)d_in[1];
    const int*   wk     = (const int*)d_in[2];

    char* ws = (char*)d_ws;
    uint2*              Apk     = (uint2*)(ws);                        // 3,211,264 B
    uint32_t*           xbT     = (uint32_t*)(ws + 3211264);           // 3,612,672 B
    unsigned long long* partial = (unsigned long long*)(ws + 6823936); //   270,336 B
    int*                argT    = (int*)(ws + 7094272);                //   147,456 B
    unsigned long long* fireM   = (unsigned long long*)(ws + 7241728); //     4,608 B

    float* out = (float*)d_out;

    hipMemsetAsync(out, 0, (size_t)out_size * 4, stream);
    hipMemsetAsync(partial, 0, NCOL * 8, stream);
    k_apack<<<1568, 256, 0, stream>>>(weight, Apk);
    k_xbitsT<<<3136, 256, 0, stream>>>(x, xbT);
    k_gemm<<<dim3(NCOL / 64), 256, 0, stream>>>((const i32x4*)Apk, xbT, wk, partial);
    k_fire<<<144, 256, 0, stream>>>(partial, argT, fireM);
    k_scan<<<1, 64, 0, stream>>>(fireM, argT, out);
}

// Round 2
// 449.634 us; speedup vs baseline: 1.4304x; 1.4304x over previous
//
#include <hip/hip_runtime.h>
#include <stdint.h>

#define NEURONS 512
#define SYN     784
#define TIN     500
#define TP      522
#define TPAD    528
#define BATCH   64
#define NCOL    (BATCH*TPAD)   // 33792
#define XW2     18             // xbT words per (b,*,s): word0 guard, 1..16 data, 17 guard
#define NKK     98             // K iterations (6272 / 64)

typedef int i32x4 __attribute__((ext_vector_type(4)));

// ---------------------------------------------------------------- A pack
// One-hot int8 weights, MFMA-fragment-packed (verified R3/R4):
// uint2 slot u <-> (kk, rowblk, quad, m=l15, half): byte k = s*8+w mapping.
__global__ void k_apack(const int* __restrict__ w, uint2* __restrict__ apk) {
    int u = blockIdx.x * 256 + threadIdx.x;            // 401408 slots
    int half = u & 1, m = (u >> 1) & 15, quad = (u >> 5) & 3;
    int rowblk = (u >> 7) & 31, kk = u >> 12;
    int n = rowblk * 16 + m;
    int s = kk * 8 + quad * 2 + half;
    int wv = w[n * SYN + s];
    uint2 v;
    v.x = (wv < 4)  ? (1u << (8 * wv))       : 0u;
    v.y = (wv >= 4) ? (1u << (8 * (wv - 4))) : 0u;
    apk[u] = v;
}

// ---------------------------------------------------------------- spike bits, transposed
// xbT[(b*18 + word)*784 + s]; word 0,17 guards; word w in 1..16: bit j = spike at
// tau=(w-1)*32+j. Coalesced: LDS nibble transpose, 16 rows per 256-thr block.
__global__ void k_xbitsT(const float* __restrict__ x, uint32_t* __restrict__ xbT) {
    __shared__ unsigned char nib[16][128];
    int tid = threadIdx.x;
    int r0  = blockIdx.x * 16;                         // 3136 blocks, 784%16==0 -> b uniform
    for (int e = tid; e < 2048; e += 256) {
        int row = e >> 7, q4 = e & 127;
        unsigned char v = 0;
        if (q4 < 125) {
            float4 f = *(const float4*)(x + (size_t)(r0 + row) * TIN + q4 * 4);
            v = (unsigned char)((f.x != 0.f) | ((f.y != 0.f) << 1) |
                                ((f.z != 0.f) << 2) | ((f.w != 0.f) << 3));
        }
        nib[row][q4] = v;
    }
    __syncthreads();
    int row = tid >> 4, d = tid & 15;
    uint64_t u = *(const uint64_t*)&nib[row][d * 8];
    uint32_t wd = 0;
#pragma unroll
    for (int q = 0; q < 8; ++q)
        wd |= ((uint32_t)((u >> (8 * q)) & 0xFull)) << (4 * q);
    if (d == 15) wd &= 0xFFFFFu;                       // taus 480..499 only
    int grow = r0 + row;
    int b = grow / SYN, s = grow - b * SYN;
    xbT[(size_t)(b * XW2 + 1 + d) * SYN + s] = wd;
    if (d == 0) {
        xbT[(size_t)(b * XW2) * SYN + s] = 0u;         // guard word 0
        xbT[(size_t)(b * XW2 + 17) * SYN + s] = 0u;    // guard word 17
    }
}

// ---------------------------------------------------------------- B-fragment build
// One thread per (column, synapse-pair); windows built ONCE globally (no
// duplication), predicated table gathers (p~0.42 active) -> low LDS pipe cost.
// Write layout: slot((kk*NCOL+col)*4+sp) of 16B -> GEMM reads 1KB/wave contiguous.
__global__ __launch_bounds__(256) void k_bbuild(
    const uint32_t* __restrict__ xbT,
    const int*      __restrict__ wk,
    uint4*          __restrict__ Bg)
{
    __shared__ uint2 T0[2048];           // taps 0..10 sums, packed u8 x8 (per weight)
    __shared__ uint2 T1[1024];           // taps 11..20
    __shared__ uint2 tapv[21];

    const int tid = threadIdx.x;
    if (tid < 21) {
        uint32_t lo = 0, hi = 0;
        for (int q = 0; q < 4; ++q) {
            lo |= ((uint32_t)wk[q * 21 + tid]) << (8 * q);
            hi |= ((uint32_t)wk[(q + 4) * 21 + tid]) << (8 * q);
        }
        tapv[tid] = make_uint2(lo, hi);
    }
    __syncthreads();
    for (int e = tid; e < 3072; e += 256) {
        int base_t = (e < 2048) ? 0 : 11;
        uint32_t mm = (e < 2048) ? e : (e - 2048);
        uint2 a = make_uint2(0u, 0u);
        while (mm) {
            int p = __builtin_ctz(mm);
            uint2 tv = tapv[base_t + p];
            a.x += tv.x; a.y += tv.y;
            mm &= mm - 1;
        }
        if (e < 2048) T0[e] = a; else T1[e - 2048] = a;
    }

    const int col = blockIdx.x * 64 + (tid >> 2);      // sp-minor: coalesced writes
    const int sp  = tid & 3;
    int b  = col / TPAD, t = col - b * TPAD;
    int bp = t + 11;                                   // window covers flat bits bp..bp+20
    const uint32_t xbase = (uint32_t)((b * XW2 + (bp >> 5)) * SYN + sp * 2);
    const uint32_t xsh   = (uint32_t)(bp & 31);
    __syncthreads();                                   // tables ready

    const int kk0 = blockIdx.y * 49, kk1 = kk0 + 49;
    for (int kk = kk0; kk < kk1; ++kk) {
        const uint2* px = (const uint2*)(xbT + xbase + kk * 8);
        uint2 lo = px[0];                              // word w  : (s0, s1)
        uint2 hi = px[SYN / 2];                        // word w+1: (s0, s1)
        uint32_t w0 = __builtin_amdgcn_alignbit(hi.x, lo.x, xsh) & 0x1FFFFFu;
        uint32_t w1 = __builtin_amdgcn_alignbit(hi.y, lo.y, xsh) & 0x1FFFFFu;
        uint32_t l0 = w0 & 2047u, h0 = w0 >> 11;
        uint32_t l1 = w1 & 2047u, h1 = w1 >> 11;
        uint2 a0 = make_uint2(0u, 0u), a1 = make_uint2(0u, 0u);
        if (l0) { uint2 u = T0[l0]; a0.x += u.x; a0.y += u.y; }
        if (h0) { uint2 v = T1[h0]; a0.x += v.x; a0.y += v.y; }
        if (l1) { uint2 u = T0[l1]; a1.x += u.x; a1.y += u.y; }
        if (h1) { uint2 v = T1[h1]; a1.x += v.x; a1.y += v.y; }
        Bg[(size_t)(kk * NCOL + col) * 4 + sp] = make_uint4(a0.x, a0.y, a1.x, a1.y);
    }
}

// ---------------------------------------------------------------- pure GEMM + argmax
// Barrier-free, no LDS in K-loop. 4 waves x (128 rows x 32 cols). af from L2
// (A fits per-XCD L2), bf streamed from Bg (L3) with 1-iter register prefetch.
__global__ __launch_bounds__(256) void k_gemm2(
    const i32x4* __restrict__ Apk4,
    const i32x4* __restrict__ Bg4,
    unsigned long long* __restrict__ partial)
{
    __shared__ unsigned long long red[128 * 4];

    const int tid  = threadIdx.x;
    const int lane = tid & 63;
    const int wn   = tid >> 6;           // 4 col-groups of 32
    const int quad = lane >> 4, l15 = lane & 15;
    const int m0   = blockIdx.x * 128;
    const int col0 = blockIdx.y * 128;
    const int rb0  = blockIdx.x * 8;
    const int cb   = col0 + wn * 32 + l15;   // j=0 column of this lane

    i32x4 acc[8][2];
#pragma unroll
    for (int i = 0; i < 8; ++i)
#pragma unroll
        for (int j = 0; j < 2; ++j) { i32x4 z = {0, 0, 0, 0}; acc[i][j] = z; }

    i32x4 bfn[2];
    {
        size_t nb = (size_t)cb * 4 + quad;
        bfn[0] = Bg4[nb];
        bfn[1] = Bg4[nb + 64];           // j=1: +16 cols
    }

    for (int kk = 0; kk < NKK; ++kk) {
        i32x4 af[8];
#pragma unroll
        for (int i = 0; i < 8; ++i)
            af[i] = Apk4[(size_t)(kk * 32 + rb0 + i) * 64 + lane];
        i32x4 bf[2];
        bf[0] = bfn[0]; bf[1] = bfn[1];
        if (kk + 1 < NKK) {              // prefetch next B (hides L3 latency)
            size_t nb = (size_t)((kk + 1) * NCOL + cb) * 4 + quad;
            bfn[0] = Bg4[nb];
            bfn[1] = Bg4[nb + 64];
        }
#pragma unroll
        for (int i = 0; i < 8; ++i)
#pragma unroll
            for (int j = 0; j < 2; ++j)
                acc[i][j] = __builtin_amdgcn_mfma_i32_16x16x64_i8(af[i], bf[j], acc[i][j], 0, 0, 0);
    }

    // epilogue: per-lane best over its 32 rows, then cross-quad via LDS
#pragma unroll
    for (int j = 0; j < 2; ++j) {
        unsigned long long bp = 0ull;
#pragma unroll
        for (int i = 0; i < 8; ++i)
#pragma unroll
            for (int r = 0; r < 4; ++r) {
                int grow = m0 + i * 16 + quad * 4 + r;
                unsigned long long pk =
                    (((unsigned long long)(uint32_t)acc[i][j][r]) << 32) |
                    (unsigned long long)(uint32_t)(511 - grow);
                bp = pk > bp ? pk : bp;
            }
        red[(wn * 32 + j * 16 + l15) * 4 + quad] = bp;
    }
    __syncthreads();
    if (tid < 128) {
        unsigned long long b = red[tid * 4];
#pragma unroll
        for (int u = 1; u < 4; ++u) {
            unsigned long long v = red[tid * 4 + u];
            b = v > b ? v : b;
        }
        atomicMax(&partial[col0 + tid], b);
    }
}

// ---------------------------------------------------------------- fused fallback (R0, verified 438us)
__global__ __launch_bounds__(256) void k_gemm_fused(
    const i32x4*    __restrict__ Apk4,
    const uint32_t* __restrict__ xbT,
    const int*      __restrict__ wk,
    unsigned long long* __restrict__ partial)
{
    __shared__ uint2 T0[2048];
    __shared__ uint2 T1[1024];
    __shared__ unsigned long long red[128 * 4];
    __shared__ uint2 tapv[21];

    const int tid  = threadIdx.x;
    const int lane = tid & 63;
    const int wn   = tid >> 6;
    const int quad = lane >> 4, l15 = lane & 15;
    const int m0   = blockIdx.x * 128;
    const int col0 = blockIdx.y * 128;
    const int rb0  = blockIdx.x * 8;

    if (tid < 21) {
        uint32_t lo = 0, hi = 0;
        for (int q = 0; q < 4; ++q) {
            lo |= ((uint32_t)wk[q * 21 + tid]) << (8 * q);
            hi |= ((uint32_t)wk[(q + 4) * 21 + tid]) << (8 * q);
        }
        tapv[tid] = make_uint2(lo, hi);
    }
    __syncthreads();
    for (int e = tid; e < 3072; e += 256) {
        int base_t = (e < 2048) ? 0 : 11;
        uint32_t mm = (e < 2048) ? e : (e - 2048);
        uint2 a = make_uint2(0u, 0u);
        while (mm) {
            int p = __builtin_ctz(mm);
            uint2 tv = tapv[base_t + p];
            a.x += tv.x; a.y += tv.y;
            mm &= mm - 1;
        }
        if (e < 2048) T0[e] = a; else T1[e - 2048] = a;
    }

    uint32_t base[2]; uint32_t sh[2];
#pragma unroll
    for (int j = 0; j < 2; ++j) {
        int c = col0 + wn * 32 + j * 16 + l15;
        int b = c / TPAD, t = c - b * TPAD;
        int bp = t + 11;
        base[j] = (uint32_t)((b * XW2 + (bp >> 5)) * SYN + quad * 2);
        sh[j]   = (uint32_t)(bp & 31);
    }
    __syncthreads();

    i32x4 acc[8][2];
#pragma unroll
    for (int i = 0; i < 8; ++i)
#pragma unroll
        for (int j = 0; j < 2; ++j) { i32x4 z = {0, 0, 0, 0}; acc[i][j] = z; }

    for (int kk = 0; kk < NKK; ++kk) {
        i32x4 af[8];
#pragma unroll
        for (int i = 0; i < 8; ++i)
            af[i] = Apk4[(size_t)(kk * 32 + rb0 + i) * 64 + lane];
        i32x4 bf[2];
#pragma unroll
        for (int j = 0; j < 2; ++j) {
            const uint2* px = (const uint2*)(xbT + base[j] + kk * 8);
            uint2 lo = px[0];
            uint2 hi = px[SYN / 2];
            uint32_t win0 = __builtin_amdgcn_alignbit(hi.x, lo.x, sh[j]) & 0x1FFFFFu;
            uint32_t win1 = __builtin_amdgcn_alignbit(hi.y, lo.y, sh[j]) & 0x1FFFFFu;
            uint2 u0 = T0[win0 & 2047], v0 = T1[win0 >> 11];
            uint2 u1 = T0[win1 & 2047], v1 = T1[win1 >> 11];
            i32x4 bb;
            bb[0] = (int)(u0.x + v0.x); bb[1] = (int)(u0.y + v0.y);
            bb[2] = (int)(u1.x + v1.x); bb[3] = (int)(u1.y + v1.y);
            bf[j] = bb;
        }
#pragma unroll
        for (int i = 0; i < 8; ++i)
#pragma unroll
            for (int j = 0; j < 2; ++j)
                acc[i][j] = __builtin_amdgcn_mfma_i32_16x16x64_i8(af[i], bf[j], acc[i][j], 0, 0, 0);
    }

#pragma unroll
    for (int j = 0; j < 2; ++j) {
        unsigned long long bp = 0ull;
#pragma unroll
        for (int i = 0; i < 8; ++i)
#pragma unroll
            for (int r = 0; r < 4; ++r) {
                int grow = m0 + i * 16 + quad * 4 + r;
                unsigned long long pk =
                    (((unsigned long long)(uint32_t)acc[i][j][r]) << 32) |
                    (unsigned long long)(uint32_t)(511 - grow);
                bp = pk > bp ? pk : bp;
            }
        red[(wn * 32 + j * 16 + l15) * 4 + quad] = bp;
    }
    __syncthreads();
    if (tid < 128) {
        unsigned long long b = red[tid * 4];
#pragma unroll
        for (int u = 1; u < 4; ++u) {
            unsigned long long v = red[tid * 4 + u];
            b = v > b ? v : b;
        }
        atomicMax(&partial[col0 + tid], b);
    }
}

// ---------------------------------------------------------------- fire ballot
__global__ void k_fire(const unsigned long long* __restrict__ partial,
                       int* __restrict__ argT, unsigned long long* __restrict__ fireM) {
    int id   = blockIdx.x * 4 + (threadIdx.x >> 6);   // 576 = 64 b x 9 chunks
    int lane = threadIdx.x & 63;
    int b    = id / 9, ch = id - b * 9;
    int t    = ch * 64 + lane;
    int col  = b * TPAD + (t < TPAD ? t : TPAD - 1);
    unsigned long long pv = partial[col];
    int best = (int)(pv >> 32);
    int arg  = 511 - (int)(pv & 0xFFFFFFFFull);
    argT[id * 64 + lane] = arg;
    unsigned long long f = __ballot((t < TP) && (best > 40));
    if (lane == 0) fireM[id] = f;
}

// ---------------------------------------------------------------- depression walk
__global__ void k_scan(const unsigned long long* __restrict__ fireM,
                       const int* __restrict__ argT, float* __restrict__ out) {
    int b = threadIdx.x;  // 64 lanes = 64 batches
    unsigned long long fm[9];
#pragma unroll
    for (int c = 0; c < 9; ++c) fm[c] = fireM[b * 9 + c];
    unsigned short ts[26];
    int nf = 0, dep = 0;
    for (int c = 0; c < 9; ++c) {
        unsigned long long mm = fm[c];
        int pos = 0;
        while (pos < 64) {
            if (dep > 0) {
                int adv = dep < (64 - pos) ? dep : (64 - pos);
                dep -= adv; pos += adv; mm >>= adv;    // adv <= 21 < 64
                continue;
            }
            if (mm == 0) break;
            int z = __builtin_ctzll(mm);
            pos += z; mm >>= z;
            ts[nf++] = (unsigned short)(c * 64 + pos);
            dep = 21; ++pos; mm >>= 1;
        }
    }
    for (int i = 0; i < nf; ++i) {
        int t = ts[i];
        int a = argT[(b * 9 + (t >> 6)) * 64 + (t & 63)];
        out[(size_t)b * (NEURONS * TP) + (size_t)a * TP + t] = 1.0f;
    }
}

extern "C" void kernel_launch(void* const* d_in, const int* in_sizes, int n_in,
                              void* d_out, int out_size, void* d_ws, size_t ws_size,
                              hipStream_t stream) {
    const float* x      = (const float*)d_in[0];
    const int*   weight = (const int*)d_in[1];
    const int*   wk     = (const int*)d_in[2];

    char* ws = (char*)d_ws;
    uint2*              Apk     = (uint2*)(ws);                        // 3,211,264 B
    uint32_t*           xbT     = (uint32_t*)(ws + 3211264);           // 3,612,672 B
    unsigned long long* partial = (unsigned long long*)(ws + 6823936); //   270,336 B
    int*                argT    = (int*)(ws + 7094272);                //   147,456 B
    unsigned long long* fireM   = (unsigned long long*)(ws + 7241728); //     4,608 B
    uint4*              Bg      = (uint4*)(ws + 7246336);              // 211,746,816 B
    const size_t WS_SPLIT_NEED = 7246336ull + 211746816ull;            // ~219 MB

    float* out = (float*)d_out;

    hipMemsetAsync(out, 0, (size_t)out_size * 4, stream);
    hipMemsetAsync(partial, 0, NCOL * 8, stream);
    k_apack<<<1568, 256, 0, stream>>>(weight, Apk);
    k_xbitsT<<<3136, 256, 0, stream>>>(x, xbT);
    if (ws_size >= WS_SPLIT_NEED) {
        k_bbuild<<<dim3(528, 2), 256, 0, stream>>>(xbT, wk, Bg);
        k_gemm2<<<dim3(4, 264), 256, 0, stream>>>((const i32x4*)Apk, (const i32x4*)Bg, partial);
    } else {
        k_gemm_fused<<<dim3(4, NCOL / 128), 256, 0, stream>>>((const i32x4*)Apk, xbT, wk, partial);
    }
    k_fire<<<144, 256, 0, stream>>>(partial, argT, fireM);
    k_scan<<<1, 64, 0, stream>>>(fireM, argT, out);
}

// Round 3
// 434.154 us; speedup vs baseline: 1.4814x; 1.0357x over previous
//
#include <hip/hip_runtime.h>
#include <stdint.h>

#define NEURONS 512
#define SYN     784
#define TIN     500
#define TP      522
#define TPAD    528
#define BATCH   64
#define NCOL    (BATCH*TPAD)   // 33792
#define XW2     18             // xbT words per (b,*,s): word0 guard, 1..16 data, 17 guard
#define NKK     98             // K iterations (6272 / 64)

typedef int i32x4 __attribute__((ext_vector_type(4)));

// ---------------------------------------------------------------- A pack
// One-hot int8 weights, MFMA-fragment-packed (verified R3/R4):
// uint2 slot u <-> (kk, rowblk, quad, m=l15, half): byte k = s*8+w mapping.
__global__ void k_apack(const int* __restrict__ w, uint2* __restrict__ apk) {
    int u = blockIdx.x * 256 + threadIdx.x;            // 401408 slots
    int half = u & 1, m = (u >> 1) & 15, quad = (u >> 5) & 3;
    int rowblk = (u >> 7) & 31, kk = u >> 12;
    int n = rowblk * 16 + m;
    int s = kk * 8 + quad * 2 + half;
    int wv = w[n * SYN + s];
    uint2 v;
    v.x = (wv < 4)  ? (1u << (8 * wv))       : 0u;
    v.y = (wv >= 4) ? (1u << (8 * (wv - 4))) : 0u;
    apk[u] = v;
}

// ---------------------------------------------------------------- spike bits, transposed
// xbT[(b*18 + word)*784 + s]; word 0,17 guards; word w in 1..16: bit j = spike at
// tau=(w-1)*32+j. Coalesced: LDS nibble transpose, 16 rows per 256-thr block.
__global__ void k_xbitsT(const float* __restrict__ x, uint32_t* __restrict__ xbT) {
    __shared__ unsigned char nib[16][128];
    int tid = threadIdx.x;
    int r0  = blockIdx.x * 16;                         // 3136 blocks, 784%16==0 -> b uniform
    for (int e = tid; e < 2048; e += 256) {
        int row = e >> 7, q4 = e & 127;
        unsigned char v = 0;
        if (q4 < 125) {
            float4 f = *(const float4*)(x + (size_t)(r0 + row) * TIN + q4 * 4);
            v = (unsigned char)((f.x != 0.f) | ((f.y != 0.f) << 1) |
                                ((f.z != 0.f) << 2) | ((f.w != 0.f) << 3));
        }
        nib[row][q4] = v;
    }
    __syncthreads();
    int row = tid >> 4, d = tid & 15;
    uint64_t u = *(const uint64_t*)&nib[row][d * 8];
    uint32_t wd = 0;
#pragma unroll
    for (int q = 0; q < 8; ++q)
        wd |= ((uint32_t)((u >> (8 * q)) & 0xFull)) << (4 * q);
    if (d == 15) wd &= 0xFFFFFu;                       // taus 480..499 only
    int grow = r0 + row;
    int b = grow / SYN, s = grow - b * SYN;
    xbT[(size_t)(b * XW2 + 1 + d) * SYN + s] = wd;
    if (d == 0) {
        xbT[(size_t)(b * XW2) * SYN + s] = 0u;         // guard word 0
        xbT[(size_t)(b * XW2 + 17) * SYN + s] = 0u;    // guard word 17
    }
}

// ---------------------------------------------------------------- B-fragment build
// One thread per (column, synapse-pair); windows built ONCE globally (no
// duplication), predicated table gathers (p~0.42 active) -> low LDS pipe cost.
// Write layout: slot((kk*NCOL+col)*4+sp) of 16B -> GEMM reads 1KB/wave contiguous.
__global__ __launch_bounds__(256) void k_bbuild(
    const uint32_t* __restrict__ xbT,
    const int*      __restrict__ wk,
    uint4*          __restrict__ Bg)
{
    __shared__ uint2 T0[2048];           // taps 0..10 sums, packed u8 x8 (per weight)
    __shared__ uint2 T1[1024];           // taps 11..20
    __shared__ uint2 tapv[21];

    const int tid = threadIdx.x;
    if (tid < 21) {
        uint32_t lo = 0, hi = 0;
        for (int q = 0; q < 4; ++q) {
            lo |= ((uint32_t)wk[q * 21 + tid]) << (8 * q);
            hi |= ((uint32_t)wk[(q + 4) * 21 + tid]) << (8 * q);
        }
        tapv[tid] = make_uint2(lo, hi);
    }
    __syncthreads();
    for (int e = tid; e < 3072; e += 256) {
        int base_t = (e < 2048) ? 0 : 11;
        uint32_t mm = (e < 2048) ? e : (e - 2048);
        uint2 a = make_uint2(0u, 0u);
        while (mm) {
            int p = __builtin_ctz(mm);
            uint2 tv = tapv[base_t + p];
            a.x += tv.x; a.y += tv.y;
            mm &= mm - 1;
        }
        if (e < 2048) T0[e] = a; else T1[e - 2048] = a;
    }

    const int col = blockIdx.x * 64 + (tid >> 2);      // sp-minor: coalesced writes
    const int sp  = tid & 3;
    int b  = col / TPAD, t = col - b * TPAD;
    int bp = t + 11;                                   // window covers flat bits bp..bp+20
    const uint32_t xbase = (uint32_t)((b * XW2 + (bp >> 5)) * SYN + sp * 2);
    const uint32_t xsh   = (uint32_t)(bp & 31);
    __syncthreads();                                   // tables ready

    const int kk0 = blockIdx.y * 49, kk1 = kk0 + 49;
    for (int kk = kk0; kk < kk1; ++kk) {
        const uint2* px = (const uint2*)(xbT + xbase + kk * 8);
        uint2 lo = px[0];                              // word w  : (s0, s1)
        uint2 hi = px[SYN / 2];                        // word w+1: (s0, s1)
        uint32_t w0 = __builtin_amdgcn_alignbit(hi.x, lo.x, xsh) & 0x1FFFFFu;
        uint32_t w1 = __builtin_amdgcn_alignbit(hi.y, lo.y, xsh) & 0x1FFFFFu;
        uint32_t l0 = w0 & 2047u, h0 = w0 >> 11;
        uint32_t l1 = w1 & 2047u, h1 = w1 >> 11;
        uint2 a0 = make_uint2(0u, 0u), a1 = make_uint2(0u, 0u);
        if (l0) { uint2 u = T0[l0]; a0.x += u.x; a0.y += u.y; }
        if (h0) { uint2 v = T1[h0]; a0.x += v.x; a0.y += v.y; }
        if (l1) { uint2 u = T0[l1]; a1.x += u.x; a1.y += u.y; }
        if (h1) { uint2 v = T1[h1]; a1.x += v.x; a1.y += v.y; }
        Bg[(size_t)(kk * NCOL + col) * 4 + sp] = make_uint4(a0.x, a0.y, a1.x, a1.y);
    }
}

// ---------------------------------------------------------------- pure GEMM + argmax
// Barrier-free, no LDS in K-loop. 1-D grid, XCD-sibling swizzle: the 4 row-blocks
// sharing a column group's B slice land on the SAME XCD (phys%8) and adjacent in
// launch order -> B per-kk slice L2-hits for 3 of 4 siblings. B HBM ~1x.
__global__ __launch_bounds__(256) void k_gemm2(
    const i32x4* __restrict__ Apk4,
    const i32x4* __restrict__ Bg4,
    unsigned long long* __restrict__ partial)
{
    __shared__ unsigned long long red[128 * 4];

    const int tid  = threadIdx.x;
    const int lane = tid & 63;
    const int wn   = tid >> 6;           // 4 col-groups of 32
    const int quad = lane >> 4, l15 = lane & 15;

    // phys -> (rowblk, colblk): xcd = phys&7; j = phys>>3 (0..131);
    // colblk = xcd*33 + (j>>2)  (0..263), rowblk = j&3.
    const int phys   = blockIdx.x;
    const int xcd    = phys & 7;
    const int j      = phys >> 3;
    const int colblk = xcd * 33 + (j >> 2);
    const int rowblk = j & 3;

    const int m0   = rowblk * 128;
    const int col0 = colblk * 128;
    const int rb0  = rowblk * 8;
    const int cb   = col0 + wn * 32 + l15;   // j=0 column of this lane

    i32x4 acc[8][2];
#pragma unroll
    for (int i = 0; i < 8; ++i)
#pragma unroll
        for (int jj = 0; jj < 2; ++jj) { i32x4 z = {0, 0, 0, 0}; acc[i][jj] = z; }

    i32x4 bfn[2];
    {
        size_t nb = (size_t)cb * 4 + quad;
        bfn[0] = Bg4[nb];
        bfn[1] = Bg4[nb + 64];           // j=1: +16 cols
    }

    for (int kk = 0; kk < NKK; ++kk) {
        i32x4 af[8];
#pragma unroll
        for (int i = 0; i < 8; ++i)
            af[i] = Apk4[(size_t)(kk * 32 + rb0 + i) * 64 + lane];
        i32x4 bf[2];
        bf[0] = bfn[0]; bf[1] = bfn[1];
        if (kk + 1 < NKK) {              // prefetch next B (hides L2/HBM latency)
            size_t nb = (size_t)((kk + 1) * NCOL + cb) * 4 + quad;
            bfn[0] = Bg4[nb];
            bfn[1] = Bg4[nb + 64];
        }
#pragma unroll
        for (int i = 0; i < 8; ++i)
#pragma unroll
            for (int jj = 0; jj < 2; ++jj)
                acc[i][jj] = __builtin_amdgcn_mfma_i32_16x16x64_i8(af[i], bf[jj], acc[i][jj], 0, 0, 0);
    }

    // epilogue: per-lane best over its 32 rows, then cross-quad via LDS
#pragma unroll
    for (int jj = 0; jj < 2; ++jj) {
        unsigned long long bp = 0ull;
#pragma unroll
        for (int i = 0; i < 8; ++i)
#pragma unroll
            for (int r = 0; r < 4; ++r) {
                int grow = m0 + i * 16 + quad * 4 + r;
                unsigned long long pk =
                    (((unsigned long long)(uint32_t)acc[i][jj][r]) << 32) |
                    (unsigned long long)(uint32_t)(511 - grow);
                bp = pk > bp ? pk : bp;
            }
        red[(wn * 32 + jj * 16 + l15) * 4 + quad] = bp;
    }
    __syncthreads();
    if (tid < 128) {
        unsigned long long b = red[tid * 4];
#pragma unroll
        for (int u = 1; u < 4; ++u) {
            unsigned long long v = red[tid * 4 + u];
            b = v > b ? v : b;
        }
        atomicMax(&partial[col0 + tid], b);
    }
}

// ---------------------------------------------------------------- fused fallback (R0, verified 438us)
__global__ __launch_bounds__(256) void k_gemm_fused(
    const i32x4*    __restrict__ Apk4,
    const uint32_t* __restrict__ xbT,
    const int*      __restrict__ wk,
    unsigned long long* __restrict__ partial)
{
    __shared__ uint2 T0[2048];
    __shared__ uint2 T1[1024];
    __shared__ unsigned long long red[128 * 4];
    __shared__ uint2 tapv[21];

    const int tid  = threadIdx.x;
    const int lane = tid & 63;
    const int wn   = tid >> 6;
    const int quad = lane >> 4, l15 = lane & 15;
    const int m0   = blockIdx.x * 128;
    const int col0 = blockIdx.y * 128;
    const int rb0  = blockIdx.x * 8;

    if (tid < 21) {
        uint32_t lo = 0, hi = 0;
        for (int q = 0; q < 4; ++q) {
            lo |= ((uint32_t)wk[q * 21 + tid]) << (8 * q);
            hi |= ((uint32_t)wk[(q + 4) * 21 + tid]) << (8 * q);
        }
        tapv[tid] = make_uint2(lo, hi);
    }
    __syncthreads();
    for (int e = tid; e < 3072; e += 256) {
        int base_t = (e < 2048) ? 0 : 11;
        uint32_t mm = (e < 2048) ? e : (e - 2048);
        uint2 a = make_uint2(0u, 0u);
        while (mm) {
            int p = __builtin_ctz(mm);
            uint2 tv = tapv[base_t + p];
            a.x += tv.x; a.y += tv.y;
            mm &= mm - 1;
        }
        if (e < 2048) T0[e] = a; else T1[e - 2048] = a;
    }

    uint32_t base[2]; uint32_t sh[2];
#pragma unroll
    for (int j = 0; j < 2; ++j) {
        int c = col0 + wn * 32 + j * 16 + l15;
        int b = c / TPAD, t = c - b * TPAD;
        int bp = t + 11;
        base[j] = (uint32_t)((b * XW2 + (bp >> 5)) * SYN + quad * 2);
        sh[j]   = (uint32_t)(bp & 31);
    }
    __syncthreads();

    i32x4 acc[8][2];
#pragma unroll
    for (int i = 0; i < 8; ++i)
#pragma unroll
        for (int j = 0; j < 2; ++j) { i32x4 z = {0, 0, 0, 0}; acc[i][j] = z; }

    for (int kk = 0; kk < NKK; ++kk) {
        i32x4 af[8];
#pragma unroll
        for (int i = 0; i < 8; ++i)
            af[i] = Apk4[(size_t)(kk * 32 + rb0 + i) * 64 + lane];
        i32x4 bf[2];
#pragma unroll
        for (int j = 0; j < 2; ++j) {
            const uint2* px = (const uint2*)(xbT + base[j] + kk * 8);
            uint2 lo = px[0];
            uint2 hi = px[SYN / 2];
            uint32_t win0 = __builtin_amdgcn_alignbit(hi.x, lo.x, sh[j]) & 0x1FFFFFu;
            uint32_t win1 = __builtin_amdgcn_alignbit(hi.y, lo.y, sh[j]) & 0x1FFFFFu;
            uint2 u0 = T0[win0 & 2047], v0 = T1[win0 >> 11];
            uint2 u1 = T0[win1 & 2047], v1 = T1[win1 >> 11];
            i32x4 bb;
            bb[0] = (int)(u0.x + v0.x); bb[1] = (int)(u0.y + v0.y);
            bb[2] = (int)(u1.x + v1.x); bb[3] = (int)(u1.y + v1.y);
            bf[j] = bb;
        }
#pragma unroll
        for (int i = 0; i < 8; ++i)
#pragma unroll
            for (int j = 0; j < 2; ++j)
                acc[i][j] = __builtin_amdgcn_mfma_i32_16x16x64_i8(af[i], bf[j], acc[i][j], 0, 0, 0);
    }

#pragma unroll
    for (int j = 0; j < 2; ++j) {
        unsigned long long bp = 0ull;
#pragma unroll
        for (int i = 0; i < 8; ++i)
#pragma unroll
            for (int r = 0; r < 4; ++r) {
                int grow = m0 + i * 16 + quad * 4 + r;
                unsigned long long pk =
                    (((unsigned long long)(uint32_t)acc[i][j][r]) << 32) |
                    (unsigned long long)(uint32_t)(511 - grow);
                bp = pk > bp ? pk : bp;
            }
        red[(wn * 32 + j * 16 + l15) * 4 + quad] = bp;
    }
    __syncthreads();
    if (tid < 128) {
        unsigned long long b = red[tid * 4];
#pragma unroll
        for (int u = 1; u < 4; ++u) {
            unsigned long long v = red[tid * 4 + u];
            b = v > b ? v : b;
        }
        atomicMax(&partial[col0 + tid], b);
    }
}

// ---------------------------------------------------------------- fire ballot
__global__ void k_fire(const unsigned long long* __restrict__ partial,
                       int* __restrict__ argT, unsigned long long* __restrict__ fireM) {
    int id   = blockIdx.x * 4 + (threadIdx.x >> 6);   // 576 = 64 b x 9 chunks
    int lane = threadIdx.x & 63;
    int b    = id / 9, ch = id - b * 9;
    int t    = ch * 64 + lane;
    int col  = b * TPAD + (t < TPAD ? t : TPAD - 1);
    unsigned long long pv = partial[col];
    int best = (int)(pv >> 32);
    int arg  = 511 - (int)(pv & 0xFFFFFFFFull);
    argT[id * 64 + lane] = arg;
    unsigned long long f = __ballot((t < TP) && (best > 40));
    if (lane == 0) fireM[id] = f;
}

// ---------------------------------------------------------------- depression walk
__global__ void k_scan(const unsigned long long* __restrict__ fireM,
                       const int* __restrict__ argT, float* __restrict__ out) {
    int b = threadIdx.x;  // 64 lanes = 64 batches
    unsigned long long fm[9];
#pragma unroll
    for (int c = 0; c < 9; ++c) fm[c] = fireM[b * 9 + c];
    unsigned short ts[26];
    int nf = 0, dep = 0;
    for (int c = 0; c < 9; ++c) {
        unsigned long long mm = fm[c];
        int pos = 0;
        while (pos < 64) {
            if (dep > 0) {
                int adv = dep < (64 - pos) ? dep : (64 - pos);
                dep -= adv; pos += adv; mm >>= adv;    // adv <= 21 < 64
                continue;
            }
            if (mm == 0) break;
            int z = __builtin_ctzll(mm);
            pos += z; mm >>= z;
            ts[nf++] = (unsigned short)(c * 64 + pos);
            dep = 21; ++pos; mm >>= 1;
        }
    }
    for (int i = 0; i < nf; ++i) {
        int t = ts[i];
        int a = argT[(b * 9 + (t >> 6)) * 64 + (t & 63)];
        out[(size_t)b * (NEURONS * TP) + (size_t)a * TP + t] = 1.0f;
    }
}

extern "C" void kernel_launch(void* const* d_in, const int* in_sizes, int n_in,
                              void* d_out, int out_size, void* d_ws, size_t ws_size,
                              hipStream_t stream) {
    const float* x      = (const float*)d_in[0];
    const int*   weight = (const int*)d_in[1];
    const int*   wk     = (const int*)d_in[2];

    char* ws = (char*)d_ws;
    uint2*              Apk     = (uint2*)(ws);                        // 3,211,264 B
    uint32_t*           xbT     = (uint32_t*)(ws + 3211264);           // 3,612,672 B
    unsigned long long* partial = (unsigned long long*)(ws + 6823936); //   270,336 B
    int*                argT    = (int*)(ws + 7094272);                //   147,456 B
    unsigned long long* fireM   = (unsigned long long*)(ws + 7241728); //     4,608 B
    uint4*              Bg      = (uint4*)(ws + 7246336);              // 211,746,816 B
    const size_t WS_SPLIT_NEED = 7246336ull + 211746816ull;            // ~219 MB

    float* out = (float*)d_out;

    hipMemsetAsync(out, 0, (size_t)out_size * 4, stream);
    hipMemsetAsync(partial, 0, NCOL * 8, stream);
    k_apack<<<1568, 256, 0, stream>>>(weight, Apk);
    k_xbitsT<<<3136, 256, 0, stream>>>(x, xbT);
    if (ws_size >= WS_SPLIT_NEED) {
        k_bbuild<<<dim3(528, 2), 256, 0, stream>>>(xbT, wk, Bg);
        k_gemm2<<<1056, 256, 0, stream>>>((const i32x4*)Apk, (const i32x4*)Bg, partial);
    } else {
        k_gemm_fused<<<dim3(4, NCOL / 128), 256, 0, stream>>>((const i32x4*)Apk, xbT, wk, partial);
    }
    k_fire<<<144, 256, 0, stream>>>(partial, argT, fireM);
    k_scan<<<1, 64, 0, stream>>>(fireM, argT, out);
}

// Round 4
// 423.358 us; speedup vs baseline: 1.5192x; 1.0255x over previous
//
#include <hip/hip_runtime.h>
#include <stdint.h>

#define NEURONS 512
#define SYN     784
#define TIN     500
#define TP      522
#define TPAD    528
#define BATCH   64
#define NCOL    (BATCH*TPAD)   // 33792
#define XW2     18             // xbT words per (b,*,s): word0 guard, 1..16 data, 17 guard
#define NKK     98             // K iterations (6272 / 64)

typedef int i32x4 __attribute__((ext_vector_type(4)));

// ---------------------------------------------------------------- A pack
// One-hot int8 weights, MFMA-fragment-packed (verified R3/R4):
// uint2 slot u <-> (kk, rowblk, quad, m=l15, half): byte k = s*8+w mapping.
__global__ void k_apack(const int* __restrict__ w, uint2* __restrict__ apk) {
    int u = blockIdx.x * 256 + threadIdx.x;            // 401408 slots
    int half = u & 1, m = (u >> 1) & 15, quad = (u >> 5) & 3;
    int rowblk = (u >> 7) & 31, kk = u >> 12;
    int n = rowblk * 16 + m;
    int s = kk * 8 + quad * 2 + half;
    int wv = w[n * SYN + s];
    uint2 v;
    v.x = (wv < 4)  ? (1u << (8 * wv))       : 0u;
    v.y = (wv >= 4) ? (1u << (8 * (wv - 4))) : 0u;
    apk[u] = v;
}

// ---------------------------------------------------------------- spike bits, transposed
// xbT[(b*18 + word)*784 + s]; word 0,17 guards; word w in 1..16: bit j = spike at
// tau=(w-1)*32+j. Coalesced: LDS nibble transpose, 16 rows per 256-thr block.
__global__ void k_xbitsT(const float* __restrict__ x, uint32_t* __restrict__ xbT) {
    __shared__ unsigned char nib[16][128];
    int tid = threadIdx.x;
    int r0  = blockIdx.x * 16;                         // 3136 blocks, 784%16==0 -> b uniform
    for (int e = tid; e < 2048; e += 256) {
        int row = e >> 7, q4 = e & 127;
        unsigned char v = 0;
        if (q4 < 125) {
            float4 f = *(const float4*)(x + (size_t)(r0 + row) * TIN + q4 * 4);
            v = (unsigned char)((f.x != 0.f) | ((f.y != 0.f) << 1) |
                                ((f.z != 0.f) << 2) | ((f.w != 0.f) << 3));
        }
        nib[row][q4] = v;
    }
    __syncthreads();
    int row = tid >> 4, d = tid & 15;
    uint64_t u = *(const uint64_t*)&nib[row][d * 8];
    uint32_t wd = 0;
#pragma unroll
    for (int q = 0; q < 8; ++q)
        wd |= ((uint32_t)((u >> (8 * q)) & 0xFull)) << (4 * q);
    if (d == 15) wd &= 0xFFFFFu;                       // taus 480..499 only
    int grow = r0 + row;
    int b = grow / SYN, s = grow - b * SYN;
    xbT[(size_t)(b * XW2 + 1 + d) * SYN + s] = wd;
    if (d == 0) {
        xbT[(size_t)(b * XW2) * SYN + s] = 0u;         // guard word 0
        xbT[(size_t)(b * XW2 + 17) * SYN + s] = 0u;    // guard word 17
    }
}

// ---------------------------------------------------------------- B-fragment build
// One thread per (column, synapse-pair); windows built ONCE globally (no
// duplication), predicated table gathers (p~0.42 active) -> low LDS pipe cost.
// Write layout: slot((kk*NCOL+col)*4+sp) of 16B -> GEMM reads 1KB/wave contiguous.
__global__ __launch_bounds__(256) void k_bbuild(
    const uint32_t* __restrict__ xbT,
    const int*      __restrict__ wk,
    uint4*          __restrict__ Bg)
{
    __shared__ uint2 T0[2048];           // taps 0..10 sums, packed u8 x8 (per weight)
    __shared__ uint2 T1[1024];           // taps 11..20
    __shared__ uint2 tapv[21];

    const int tid = threadIdx.x;
    if (tid < 21) {
        uint32_t lo = 0, hi = 0;
        for (int q = 0; q < 4; ++q) {
            lo |= ((uint32_t)wk[q * 21 + tid]) << (8 * q);
            hi |= ((uint32_t)wk[(q + 4) * 21 + tid]) << (8 * q);
        }
        tapv[tid] = make_uint2(lo, hi);
    }
    __syncthreads();
    for (int e = tid; e < 3072; e += 256) {
        int base_t = (e < 2048) ? 0 : 11;
        uint32_t mm = (e < 2048) ? e : (e - 2048);
        uint2 a = make_uint2(0u, 0u);
        while (mm) {
            int p = __builtin_ctz(mm);
            uint2 tv = tapv[base_t + p];
            a.x += tv.x; a.y += tv.y;
            mm &= mm - 1;
        }
        if (e < 2048) T0[e] = a; else T1[e - 2048] = a;
    }

    const int col = blockIdx.x * 64 + (tid >> 2);      // sp-minor: coalesced writes
    const int sp  = tid & 3;
    int b  = col / TPAD, t = col - b * TPAD;
    int bp = t + 11;                                   // window covers flat bits bp..bp+20
    const uint32_t xbase = (uint32_t)((b * XW2 + (bp >> 5)) * SYN + sp * 2);
    const uint32_t xsh   = (uint32_t)(bp & 31);
    __syncthreads();                                   // tables ready

    const int kk0 = blockIdx.y * 49, kk1 = kk0 + 49;
    for (int kk = kk0; kk < kk1; ++kk) {
        const uint2* px = (const uint2*)(xbT + xbase + kk * 8);
        uint2 lo = px[0];                              // word w  : (s0, s1)
        uint2 hi = px[SYN / 2];                        // word w+1: (s0, s1)
        uint32_t w0 = __builtin_amdgcn_alignbit(hi.x, lo.x, xsh) & 0x1FFFFFu;
        uint32_t w1 = __builtin_amdgcn_alignbit(hi.y, lo.y, xsh) & 0x1FFFFFu;
        uint32_t l0 = w0 & 2047u, h0 = w0 >> 11;
        uint32_t l1 = w1 & 2047u, h1 = w1 >> 11;
        uint2 a0 = make_uint2(0u, 0u), a1 = make_uint2(0u, 0u);
        if (l0) { uint2 u = T0[l0]; a0.x += u.x; a0.y += u.y; }
        if (h0) { uint2 v = T1[h0]; a0.x += v.x; a0.y += v.y; }
        if (l1) { uint2 u = T0[l1]; a1.x += u.x; a1.y += u.y; }
        if (h1) { uint2 v = T1[h1]; a1.x += v.x; a1.y += v.y; }
        Bg[(size_t)(kk * NCOL + col) * 4 + sp] = make_uint4(a0.x, a0.y, a1.x, a1.y);
    }
}

// ---------------------------------------------------------------- pure GEMM + argmax
// Barrier-free, no LDS in K-loop. 1-D grid, XCD-sibling swizzle (B L2-reuse,
// verified R3: FETCH 425->152MB). R4: full double-buffer software pipeline --
// af AND bf register-prefetched one kk ahead in a 2x-unrolled loop, so each
// load batch has a whole MFMA phase (~326cy) to land in (was: af consumed
// same-iteration -> per-kk L2-latency stall at 2-3 waves/SIMD).
__global__ __launch_bounds__(256) void k_gemm2(
    const i32x4* __restrict__ Apk4,
    const i32x4* __restrict__ Bg4,
    unsigned long long* __restrict__ partial)
{
    __shared__ unsigned long long red[128 * 4];

    const int tid  = threadIdx.x;
    const int lane = tid & 63;
    const int wn   = tid >> 6;           // 4 col-groups of 32
    const int quad = lane >> 4, l15 = lane & 15;

    // phys -> (rowblk, colblk): xcd = phys&7; j = phys>>3 (0..131);
    // colblk = xcd*33 + (j>>2)  (0..263), rowblk = j&3.
    const int phys   = blockIdx.x;
    const int xcd    = phys & 7;
    const int jb     = phys >> 3;
    const int colblk = xcd * 33 + (jb >> 2);
    const int rowblk = jb & 3;

    const int m0   = rowblk * 128;
    const int col0 = colblk * 128;
    const int rb0  = rowblk * 8;
    const int cb   = col0 + wn * 32 + l15;   // j=0 column of this lane

    const i32x4* pa = Apk4 + (size_t)rb0 * 64 + lane;   // af[i](kk) at +(kk*32+i)*64
    const i32x4* pb = Bg4 + (size_t)cb * 4 + quad;      // bf[j](kk) at +kk*NCOL*4 + j*64

    i32x4 acc[8][2];
#pragma unroll
    for (int i = 0; i < 8; ++i)
#pragma unroll
        for (int jj = 0; jj < 2; ++jj) { i32x4 z = {0, 0, 0, 0}; acc[i][jj] = z; }

    i32x4 afA[8], afB[8], bfA[2], bfB[2];
#pragma unroll
    for (int i = 0; i < 8; ++i) afA[i] = pa[(size_t)i * 64];
    bfA[0] = pb[0];
    bfA[1] = pb[64];
#pragma unroll
    for (int i = 0; i < 8; ++i) afB[i] = pa[(size_t)(32 + i) * 64];
    bfB[0] = pb[(size_t)NCOL * 4];
    bfB[1] = pb[(size_t)NCOL * 4 + 64];

    for (int kk = 0; kk < NKK - 2; kk += 2) {
        // compute kk from A buffers
#pragma unroll
        for (int i = 0; i < 8; ++i)
#pragma unroll
            for (int jj = 0; jj < 2; ++jj)
                acc[i][jj] = __builtin_amdgcn_mfma_i32_16x16x64_i8(afA[i], bfA[jj], acc[i][jj], 0, 0, 0);
        // refill A buffers with kk+2 (lands during kk+1's MFMA phase)
#pragma unroll
        for (int i = 0; i < 8; ++i) afA[i] = pa[(size_t)((kk + 2) * 32 + i) * 64];
        bfA[0] = pb[(size_t)(kk + 2) * NCOL * 4];
        bfA[1] = pb[(size_t)(kk + 2) * NCOL * 4 + 64];
        // compute kk+1 from B buffers
#pragma unroll
        for (int i = 0; i < 8; ++i)
#pragma unroll
            for (int jj = 0; jj < 2; ++jj)
                acc[i][jj] = __builtin_amdgcn_mfma_i32_16x16x64_i8(afB[i], bfB[jj], acc[i][jj], 0, 0, 0);
        // refill B buffers with kk+3
#pragma unroll
        for (int i = 0; i < 8; ++i) afB[i] = pa[(size_t)((kk + 3) * 32 + i) * 64];
        bfB[0] = pb[(size_t)(kk + 3) * NCOL * 4];
        bfB[1] = pb[(size_t)(kk + 3) * NCOL * 4 + 64];
    }
    // epilogue: kk = 96 (A buffers), 97 (B buffers)
#pragma unroll
    for (int i = 0; i < 8; ++i)
#pragma unroll
        for (int jj = 0; jj < 2; ++jj)
            acc[i][jj] = __builtin_amdgcn_mfma_i32_16x16x64_i8(afA[i], bfA[jj], acc[i][jj], 0, 0, 0);
#pragma unroll
    for (int i = 0; i < 8; ++i)
#pragma unroll
        for (int jj = 0; jj < 2; ++jj)
            acc[i][jj] = __builtin_amdgcn_mfma_i32_16x16x64_i8(afB[i], bfB[jj], acc[i][jj], 0, 0, 0);

    // epilogue: per-lane best over its 32 rows, then cross-quad via LDS
#pragma unroll
    for (int jj = 0; jj < 2; ++jj) {
        unsigned long long bp = 0ull;
#pragma unroll
        for (int i = 0; i < 8; ++i)
#pragma unroll
            for (int r = 0; r < 4; ++r) {
                int grow = m0 + i * 16 + quad * 4 + r;
                unsigned long long pk =
                    (((unsigned long long)(uint32_t)acc[i][jj][r]) << 32) |
                    (unsigned long long)(uint32_t)(511 - grow);
                bp = pk > bp ? pk : bp;
            }
        red[(wn * 32 + jj * 16 + l15) * 4 + quad] = bp;
    }
    __syncthreads();
    if (tid < 128) {
        unsigned long long b = red[tid * 4];
#pragma unroll
        for (int u = 1; u < 4; ++u) {
            unsigned long long v = red[tid * 4 + u];
            b = v > b ? v : b;
        }
        atomicMax(&partial[col0 + tid], b);
    }
}

// ---------------------------------------------------------------- fused fallback (R0, verified 438us)
__global__ __launch_bounds__(256) void k_gemm_fused(
    const i32x4*    __restrict__ Apk4,
    const uint32_t* __restrict__ xbT,
    const int*      __restrict__ wk,
    unsigned long long* __restrict__ partial)
{
    __shared__ uint2 T0[2048];
    __shared__ uint2 T1[1024];
    __shared__ unsigned long long red[128 * 4];
    __shared__ uint2 tapv[21];

    const int tid  = threadIdx.x;
    const int lane = tid & 63;
    const int wn   = tid >> 6;
    const int quad = lane >> 4, l15 = lane & 15;
    const int m0   = blockIdx.x * 128;
    const int col0 = blockIdx.y * 128;
    const int rb0  = blockIdx.x * 8;

    if (tid < 21) {
        uint32_t lo = 0, hi = 0;
        for (int q = 0; q < 4; ++q) {
            lo |= ((uint32_t)wk[q * 21 + tid]) << (8 * q);
            hi |= ((uint32_t)wk[(q + 4) * 21 + tid]) << (8 * q);
        }
        tapv[tid] = make_uint2(lo, hi);
    }
    __syncthreads();
    for (int e = tid; e < 3072; e += 256) {
        int base_t = (e < 2048) ? 0 : 11;
        uint32_t mm = (e < 2048) ? e : (e - 2048);
        uint2 a = make_uint2(0u, 0u);
        while (mm) {
            int p = __builtin_ctz(mm);
            uint2 tv = tapv[base_t + p];
            a.x += tv.x; a.y += tv.y;
            mm &= mm - 1;
        }
        if (e < 2048) T0[e] = a; else T1[e - 2048] = a;
    }

    uint32_t base[2]; uint32_t sh[2];
#pragma unroll
    for (int j = 0; j < 2; ++j) {
        int c = col0 + wn * 32 + j * 16 + l15;
        int b = c / TPAD, t = c - b * TPAD;
        int bp = t + 11;
        base[j] = (uint32_t)((b * XW2 + (bp >> 5)) * SYN + quad * 2);
        sh[j]   = (uint32_t)(bp & 31);
    }
    __syncthreads();

    i32x4 acc[8][2];
#pragma unroll
    for (int i = 0; i < 8; ++i)
#pragma unroll
        for (int j = 0; j < 2; ++j) { i32x4 z = {0, 0, 0, 0}; acc[i][j] = z; }

    for (int kk = 0; kk < NKK; ++kk) {
        i32x4 af[8];
#pragma unroll
        for (int i = 0; i < 8; ++i)
            af[i] = Apk4[(size_t)(kk * 32 + rb0 + i) * 64 + lane];
        i32x4 bf[2];
#pragma unroll
        for (int j = 0; j < 2; ++j) {
            const uint2* px = (const uint2*)(xbT + base[j] + kk * 8);
            uint2 lo = px[0];
            uint2 hi = px[SYN / 2];
            uint32_t win0 = __builtin_amdgcn_alignbit(hi.x, lo.x, sh[j]) & 0x1FFFFFu;
            uint32_t win1 = __builtin_amdgcn_alignbit(hi.y, lo.y, sh[j]) & 0x1FFFFFu;
            uint2 u0 = T0[win0 & 2047], v0 = T1[win0 >> 11];
            uint2 u1 = T0[win1 & 2047], v1 = T1[win1 >> 11];
            i32x4 bb;
            bb[0] = (int)(u0.x + v0.x); bb[1] = (int)(u0.y + v0.y);
            bb[2] = (int)(u1.x + v1.x); bb[3] = (int)(u1.y + v1.y);
            bf[j] = bb;
        }
#pragma unroll
        for (int i = 0; i < 8; ++i)
#pragma unroll
            for (int j = 0; j < 2; ++j)
                acc[i][j] = __builtin_amdgcn_mfma_i32_16x16x64_i8(af[i], bf[j], acc[i][j], 0, 0, 0);
    }

#pragma unroll
    for (int j = 0; j < 2; ++j) {
        unsigned long long bp = 0ull;
#pragma unroll
        for (int i = 0; i < 8; ++i)
#pragma unroll
            for (int r = 0; r < 4; ++r) {
                int grow = m0 + i * 16 + quad * 4 + r;
                unsigned long long pk =
                    (((unsigned long long)(uint32_t)acc[i][j][r]) << 32) |
                    (unsigned long long)(uint32_t)(511 - grow);
                bp = pk > bp ? pk : bp;
            }
        red[(wn * 32 + j * 16 + l15) * 4 + quad] = bp;
    }
    __syncthreads();
    if (tid < 128) {
        unsigned long long b = red[tid * 4];
#pragma unroll
        for (int u = 1; u < 4; ++u) {
            unsigned long long v = red[tid * 4 + u];
            b = v > b ? v : b;
        }
        atomicMax(&partial[col0 + tid], b);
    }
}

// ---------------------------------------------------------------- fire ballot
__global__ void k_fire(const unsigned long long* __restrict__ partial,
                       int* __restrict__ argT, unsigned long long* __restrict__ fireM) {
    int id   = blockIdx.x * 4 + (threadIdx.x >> 6);   // 576 = 64 b x 9 chunks
    int lane = threadIdx.x & 63;
    int b    = id / 9, ch = id - b * 9;
    int t    = ch * 64 + lane;
    int col  = b * TPAD + (t < TPAD ? t : TPAD - 1);
    unsigned long long pv = partial[col];
    int best = (int)(pv >> 32);
    int arg  = 511 - (int)(pv & 0xFFFFFFFFull);
    argT[id * 64 + lane] = arg;
    unsigned long long f = __ballot((t < TP) && (best > 40));
    if (lane == 0) fireM[id] = f;
}

// ---------------------------------------------------------------- depression walk
__global__ void k_scan(const unsigned long long* __restrict__ fireM,
                       const int* __restrict__ argT, float* __restrict__ out) {
    int b = threadIdx.x;  // 64 lanes = 64 batches
    unsigned long long fm[9];
#pragma unroll
    for (int c = 0; c < 9; ++c) fm[c] = fireM[b * 9 + c];
    unsigned short ts[26];
    int nf = 0, dep = 0;
    for (int c = 0; c < 9; ++c) {
        unsigned long long mm = fm[c];
        int pos = 0;
        while (pos < 64) {
            if (dep > 0) {
                int adv = dep < (64 - pos) ? dep : (64 - pos);
                dep -= adv; pos += adv; mm >>= adv;    // adv <= 21 < 64
                continue;
            }
            if (mm == 0) break;
            int z = __builtin_ctzll(mm);
            pos += z; mm >>= z;
            ts[nf++] = (unsigned short)(c * 64 + pos);
            dep = 21; ++pos; mm >>= 1;
        }
    }
    for (int i = 0; i < nf; ++i) {
        int t = ts[i];
        int a = argT[(b * 9 + (t >> 6)) * 64 + (t & 63)];
        out[(size_t)b * (NEURONS * TP) + (size_t)a * TP + t] = 1.0f;
    }
}

extern "C" void kernel_launch(void* const* d_in, const int* in_sizes, int n_in,
                              void* d_out, int out_size, void* d_ws, size_t ws_size,
                              hipStream_t stream) {
    const float* x      = (const float*)d_in[0];
    const int*   weight = (const int*)d_in[1];
    const int*   wk     = (const int*)d_in[2];

    char* ws = (char*)d_ws;
    uint2*              Apk     = (uint2*)(ws);                        // 3,211,264 B
    uint32_t*           xbT     = (uint32_t*)(ws + 3211264);           // 3,612,672 B
    unsigned long long* partial = (unsigned long long*)(ws + 6823936); //   270,336 B
    int*                argT    = (int*)(ws + 7094272);                //   147,456 B
    unsigned long long* fireM   = (unsigned long long*)(ws + 7241728); //     4,608 B
    uint4*              Bg      = (uint4*)(ws + 7246336);              // 211,746,816 B
    const size_t WS_SPLIT_NEED = 7246336ull + 211746816ull;            // ~219 MB

    float* out = (float*)d_out;

    hipMemsetAsync(out, 0, (size_t)out_size * 4, stream);
    hipMemsetAsync(partial, 0, NCOL * 8, stream);
    k_apack<<<1568, 256, 0, stream>>>(weight, Apk);
    k_xbitsT<<<3136, 256, 0, stream>>>(x, xbT);
    if (ws_size >= WS_SPLIT_NEED) {
        k_bbuild<<<dim3(528, 2), 256, 0, stream>>>(xbT, wk, Bg);
        k_gemm2<<<1056, 256, 0, stream>>>((const i32x4*)Apk, (const i32x4*)Bg, partial);
    } else {
        k_gemm_fused<<<dim3(4, NCOL / 128), 256, 0, stream>>>((const i32x4*)Apk, xbT, wk, partial);
    }
    k_fire<<<144, 256, 0, stream>>>(partial, argT, fireM);
    k_scan<<<1, 64, 0, stream>>>(fireM, argT, out);
}